// Round 5
// baseline (1887.486 us; speedup 1.0000x reference)
//
#include <hip/hip_runtime.h>
#include <math.h>

// Problem constants (uniform scenes per reference)
#define NB 768      // batch = S*P
#define NS 32       // scenes
#define NP 24       // peds/scene
#define ED 64       // embedding dim E
#define HD 128      // hidden H
#define G4 512      // 4*H
#define BNKD 1024   // bottleneck
#define KM1 1152    // H + BNK
#define KG 192      // E + H (LSTM gate K)
#define TSTEPS 12

typedef __bf16 bf16x8 __attribute__((ext_vector_type(8)));
typedef float f32x4 __attribute__((ext_vector_type(4)));
typedef unsigned short u16x8 __attribute__((ext_vector_type(8)));

__device__ __forceinline__ unsigned short f2bf(float f) {
  unsigned u = __float_as_uint(f);
  u = (u + 0x7FFFu + ((u >> 16) & 1u)) >> 16;   // RNE
  return (unsigned short)u;
}
__device__ __forceinline__ unsigned pack2bf(float a, float b) {
  return (unsigned)f2bf(a) | ((unsigned)f2bf(b) << 16);
}
__device__ __forceinline__ float bf2f(unsigned short h) {
  return __uint_as_float(((unsigned)h) << 16);
}

// ---------------------------------------------------------------------------
// init: carries, dec_in0, folded pool-L1 weights, and bf16 weight prepacks:
// W2T[n][k]=W_p2[k][n]; W1T[n][k]=W_m1[k][n]; WmT[n][k]=W_m2[k][n];
// WgT hi/lo [512][192] = [W_ih;W_hh]^T; Wp1T hi/lo [512][128] = W_p1[64:]^T;
// bg = b_ih + b_hh.
// ---------------------------------------------------------------------------
__global__ void init_kernel(const float* __restrict__ last_pos,
                            const float* __restrict__ last_pos_rel,
                            const float* __restrict__ c0,
                            const float* __restrict__ W_se,
                            const float* __restrict__ b_se,
                            const float* __restrict__ W_pse,
                            const float* __restrict__ b_pse,
                            const float* __restrict__ W_p1,
                            const float* __restrict__ b_p1,
                            const float* __restrict__ W_p2,
                            const float* __restrict__ W_m1,
                            const float* __restrict__ W_m2,
                            const float* __restrict__ W_ih,
                            const float* __restrict__ W_hh,
                            const float* __restrict__ b_ih,
                            const float* __restrict__ b_hh,
                            float* __restrict__ ccar,
                            float* __restrict__ din, float* __restrict__ lpos,
                            float* __restrict__ Wc, float* __restrict__ bc,
                            unsigned short* __restrict__ W2T,
                            unsigned short* __restrict__ W1T,
                            unsigned short* __restrict__ WmT,
                            unsigned short* __restrict__ WgT_hi,
                            unsigned short* __restrict__ WgT_lo,
                            unsigned short* __restrict__ Wp1T_hi,
                            unsigned short* __restrict__ Wp1T_lo,
                            float* __restrict__ bg) {
  int stride = gridDim.x * blockDim.x;
  int idx0 = blockIdx.x * blockDim.x + threadIdx.x;
  for (int i = idx0; i < NB * HD; i += stride) ccar[i] = c0[i];
  for (int i = idx0; i < NB * 2; i += stride) lpos[i] = last_pos[i];
  for (int i = idx0; i < NB * ED; i += stride) {
    int r = i >> 6, e = i & 63;
    din[i] = b_se[e] + last_pos_rel[2 * r] * W_se[e]
                     + last_pos_rel[2 * r + 1] * W_se[ED + e];
  }
  for (int n = idx0; n < G4; n += stride) {
    float w0 = 0.f, w1 = 0.f, bb = b_p1[n];
    for (int e = 0; e < ED; ++e) {
      float wp = W_p1[e * G4 + n];
      w0 += W_pse[e] * wp;
      w1 += W_pse[ED + e] * wp;
      bb += b_pse[e] * wp;
    }
    Wc[n] = w0; Wc[G4 + n] = w1; bc[n] = bb;
  }
  for (int n = idx0; n < G4; n += stride) bg[n] = b_ih[n] + b_hh[n];
  // W2T: 1024 n x 512 k bf16
  for (int idx = idx0; idx < 1024 * 64; idx += stride) {
    int n = idx & 1023, k0 = (idx >> 10) << 3;
    unsigned pk0 = pack2bf(W_p2[(k0 + 0) * BNKD + n], W_p2[(k0 + 1) * BNKD + n]);
    unsigned pk1 = pack2bf(W_p2[(k0 + 2) * BNKD + n], W_p2[(k0 + 3) * BNKD + n]);
    unsigned pk2 = pack2bf(W_p2[(k0 + 4) * BNKD + n], W_p2[(k0 + 5) * BNKD + n]);
    unsigned pk3 = pack2bf(W_p2[(k0 + 6) * BNKD + n], W_p2[(k0 + 7) * BNKD + n]);
    *(uint4*)&W2T[n * G4 + k0] = make_uint4(pk0, pk1, pk2, pk3);
  }
  // W1T: 1024 n x 1152 k bf16
  for (int idx = idx0; idx < 1024 * 144; idx += stride) {
    int n = idx & 1023, k0 = (idx >> 10) << 3;
    unsigned pk0 = pack2bf(W_m1[(k0 + 0) * BNKD + n], W_m1[(k0 + 1) * BNKD + n]);
    unsigned pk1 = pack2bf(W_m1[(k0 + 2) * BNKD + n], W_m1[(k0 + 3) * BNKD + n]);
    unsigned pk2 = pack2bf(W_m1[(k0 + 4) * BNKD + n], W_m1[(k0 + 5) * BNKD + n]);
    unsigned pk3 = pack2bf(W_m1[(k0 + 6) * BNKD + n], W_m1[(k0 + 7) * BNKD + n]);
    *(uint4*)&W1T[n * KM1 + k0] = make_uint4(pk0, pk1, pk2, pk3);
  }
  // WmT: 128 n x 1024 k bf16   (W_m2 is [1024][128])
  for (int idx = idx0; idx < 128 * 128; idx += stride) {
    int n = idx & 127, k0 = (idx >> 7) << 3;
    unsigned pk0 = pack2bf(W_m2[(k0 + 0) * HD + n], W_m2[(k0 + 1) * HD + n]);
    unsigned pk1 = pack2bf(W_m2[(k0 + 2) * HD + n], W_m2[(k0 + 3) * HD + n]);
    unsigned pk2 = pack2bf(W_m2[(k0 + 4) * HD + n], W_m2[(k0 + 5) * HD + n]);
    unsigned pk3 = pack2bf(W_m2[(k0 + 6) * HD + n], W_m2[(k0 + 7) * HD + n]);
    *(uint4*)&WmT[n * BNKD + k0] = make_uint4(pk0, pk1, pk2, pk3);
  }
  // WgT hi/lo: [512 n][192 k], k<64 from W_ih, k>=64 from W_hh
  for (int idx = idx0; idx < 512 * 24; idx += stride) {
    int n = idx & 511, k0 = (idx >> 9) << 3;
    unsigned short hi[8], lo[8];
#pragma unroll
    for (int q = 0; q < 8; ++q) {
      int k = k0 + q;
      float w = (k < ED) ? W_ih[k * G4 + n] : W_hh[(k - ED) * G4 + n];
      unsigned short h = f2bf(w);
      hi[q] = h;
      lo[q] = f2bf(w - bf2f(h));
    }
    uint4 ph_, pl_;
    ph_.x = hi[0] | (hi[1] << 16); ph_.y = hi[2] | (hi[3] << 16);
    ph_.z = hi[4] | (hi[5] << 16); ph_.w = hi[6] | (hi[7] << 16);
    pl_.x = lo[0] | (lo[1] << 16); pl_.y = lo[2] | (lo[3] << 16);
    pl_.z = lo[4] | (lo[5] << 16); pl_.w = lo[6] | (lo[7] << 16);
    *(uint4*)&WgT_hi[n * KG + k0] = ph_;
    *(uint4*)&WgT_lo[n * KG + k0] = pl_;
  }
  // Wp1T hi/lo: [512 n][128 k] from W_p1 rows 64..191
  for (int idx = idx0; idx < 512 * 16; idx += stride) {
    int n = idx & 511, k0 = (idx >> 9) << 3;
    unsigned short hi[8], lo[8];
#pragma unroll
    for (int q = 0; q < 8; ++q) {
      float w = W_p1[(ED + k0 + q) * G4 + n];
      unsigned short h = f2bf(w);
      hi[q] = h;
      lo[q] = f2bf(w - bf2f(h));
    }
    uint4 ph_, pl_;
    ph_.x = hi[0] | (hi[1] << 16); ph_.y = hi[2] | (hi[3] << 16);
    ph_.z = hi[4] | (hi[5] << 16); ph_.w = hi[6] | (hi[7] << 16);
    pl_.x = lo[0] | (lo[1] << 16); pl_.y = lo[2] | (lo[3] << 16);
    pl_.z = lo[4] | (lo[5] << 16); pl_.w = lo[6] | (lo[7] << 16);
    *(uint4*)&Wp1T_hi[n * HD + k0] = ph_;
    *(uint4*)&Wp1T_lo[n * HD + k0] = pl_;
  }
}

// ---------------------------------------------------------------------------
// helpers: build hi/lo bf16x8 A-fragments from 8 fp32 values
// ---------------------------------------------------------------------------
__device__ __forceinline__ void split8(const float4 x0, const float4 x1,
                                       bf16x8& ah, bf16x8& al) {
  float v[8] = {x0.x, x0.y, x0.z, x0.w, x1.x, x1.y, x1.z, x1.w};
#pragma unroll
  for (int q = 0; q < 8; ++q) {
    __bf16 h = (__bf16)v[q];
    ah[q] = h;
    al[q] = (__bf16)(v[q] - (float)h);
  }
}

// ---------------------------------------------------------------------------
// step_a_mfma: LSTM gates + cell + hidden2pos + dec_in_next + Hp1 (+bc),
// all per-block for 16 batch rows. MFMA with hi/lo bf16 (3-term) for
// gates and Hp1. Grid 48, 256 threads (4 waves, N-split 128 each).
// ---------------------------------------------------------------------------
__global__ __launch_bounds__(256) void step_a_mfma(
    const float* __restrict__ hprev, const float* __restrict__ cprev,
    const float* __restrict__ din, const float* __restrict__ lpos_in,
    const unsigned short* __restrict__ WgT_hi, const unsigned short* __restrict__ WgT_lo,
    const float* __restrict__ bg,
    const unsigned short* __restrict__ Wp1T_hi, const unsigned short* __restrict__ Wp1T_lo,
    const float* __restrict__ bc,
    const float* __restrict__ W_hp, const float* __restrict__ b_hp,
    const float* __restrict__ W_se, const float* __restrict__ b_se,
    const float* __restrict__ b_m2,
    float* __restrict__ hn, float* __restrict__ cnext,
    float* __restrict__ dnext, float* __restrict__ lpos_out,
    float* __restrict__ Hp1, float* __restrict__ pred_out,
    float* __restrict__ hacc_next, int relu_in) {
  __shared__ __align__(16) float xl[16][196];  // [din(64)|h(128)], pad->196
  __shared__ float gg[16][516];
  __shared__ __align__(16) float hl[16][132];
  __shared__ float rp[16][2];
  int t = threadIdx.x;
  int r0 = blockIdx.x * 16;

  for (int i = t; i < 16 * ED; i += 256) { int r = i >> 6, k = i & 63; xl[r][k] = din[(r0 + r) * ED + k]; }
  for (int i = t; i < 16 * HD; i += 256) {
    int r = i >> 7, k = i & 127;
    float v = hprev[(r0 + r) * HD + k];
    if (relu_in) v = fmaxf(v, 0.f);
    xl[r][ED + k] = v;
    hacc_next[(r0 + r) * HD + k] = b_m2[k];   // bias-init mlp2 accumulator
  }
  __syncthreads();

  int lane = t & 63, wn = t >> 6;
  int arow = lane & 15, ak = (lane >> 4) * 8, h = lane >> 4;
  int n0 = wn * 128;

  // ---- gates: [16 x 192] @ [192 x 512] ----
  f32x4 acc[8];
#pragma unroll
  for (int nf = 0; nf < 8; ++nf) acc[nf] = (f32x4){0.f, 0.f, 0.f, 0.f};
  const unsigned short* bh[8];
  const unsigned short* blp[8];
#pragma unroll
  for (int nf = 0; nf < 8; ++nf) {
    bh[nf]  = WgT_hi + (size_t)(n0 + nf * 16 + arow) * KG + ak;
    blp[nf] = WgT_lo + (size_t)(n0 + nf * 16 + arow) * KG + ak;
  }
#pragma unroll
  for (int kt = 0; kt < 6; ++kt) {
    float4 x0 = *(const float4*)&xl[arow][kt * 32 + ak];
    float4 x1 = *(const float4*)&xl[arow][kt * 32 + ak + 4];
    bf16x8 ah, al;
    split8(x0, x1, ah, al);
#pragma unroll
    for (int nf = 0; nf < 8; ++nf) {
      bf16x8 wh = *(const bf16x8*)(bh[nf] + kt * 32);
      bf16x8 wl = *(const bf16x8*)(blp[nf] + kt * 32);
      acc[nf] = __builtin_amdgcn_mfma_f32_16x16x32_bf16(ah, wh, acc[nf], 0, 0, 0);
      acc[nf] = __builtin_amdgcn_mfma_f32_16x16x32_bf16(ah, wl, acc[nf], 0, 0, 0);
      acc[nf] = __builtin_amdgcn_mfma_f32_16x16x32_bf16(al, wh, acc[nf], 0, 0, 0);
    }
  }
#pragma unroll
  for (int nf = 0; nf < 8; ++nf) {
    int col = n0 + nf * 16 + arow;
    float bb = bg[col];
#pragma unroll
    for (int rr = 0; rr < 4; ++rr)
      gg[h * 4 + rr][col] = acc[nf][rr] + bb;
  }
  __syncthreads();

  // ---- LSTM elementwise (gate order i,f,g,o) ----
  for (int i = t; i < 16 * HD; i += 256) {
    int r = i >> 7, k = i & 127;
    float ig = gg[r][k], fg = gg[r][HD + k], gz = gg[r][2 * HD + k], og = gg[r][3 * HD + k];
    float si = 1.f / (1.f + expf(-ig));
    float sf = 1.f / (1.f + expf(-fg));
    float so = 1.f / (1.f + expf(-og));
    float gt = tanhf(gz);
    float c = sf * cprev[(r0 + r) * HD + k] + si * gt;
    float hv = so * tanhf(c);
    cnext[(r0 + r) * HD + k] = c;
    hn[(r0 + r) * HD + k] = hv;
    hl[r][k] = hv;
  }
  __syncthreads();

  // ---- hidden2pos: rp = hl @ W_hp + b_hp (8 lanes per (r,d)) ----
  {
    int rr2 = t >> 4, d2 = (t >> 3) & 1, sub = t & 7;
    float s = 0.f;
#pragma unroll
    for (int k2 = sub * 16; k2 < sub * 16 + 16; ++k2)
      s += hl[rr2][k2] * W_hp[k2 * 2 + d2];
    s += __shfl_xor(s, 1); s += __shfl_xor(s, 2); s += __shfl_xor(s, 4);
    if (sub == 0) {
      s += b_hp[d2];
      rp[rr2][d2] = s;
      pred_out[(r0 + rr2) * 2 + d2] = s;
      lpos_out[(r0 + rr2) * 2 + d2] = s + lpos_in[(r0 + rr2) * 2 + d2];
    }
  }
  __syncthreads();

  // ---- dec_in_next ----
  for (int i = t; i < 16 * ED; i += 256) {
    int r = i >> 6, e = i & 63;
    dnext[(r0 + r) * ED + e] = b_se[e] + rp[r][0] * W_se[e] + rp[r][1] * W_se[ED + e];
  }

  // ---- Hp1 = h_new @ W_p1[64:] + bc ----
  f32x4 acc2[8];
#pragma unroll
  for (int nf = 0; nf < 8; ++nf) acc2[nf] = (f32x4){0.f, 0.f, 0.f, 0.f};
  const unsigned short* ph_[8];
  const unsigned short* pl_[8];
#pragma unroll
  for (int nf = 0; nf < 8; ++nf) {
    ph_[nf] = Wp1T_hi + (size_t)(n0 + nf * 16 + arow) * HD + ak;
    pl_[nf] = Wp1T_lo + (size_t)(n0 + nf * 16 + arow) * HD + ak;
  }
#pragma unroll
  for (int kt = 0; kt < 4; ++kt) {
    float4 x0 = *(const float4*)&hl[arow][kt * 32 + ak];
    float4 x1 = *(const float4*)&hl[arow][kt * 32 + ak + 4];
    bf16x8 ah, al;
    split8(x0, x1, ah, al);
#pragma unroll
    for (int nf = 0; nf < 8; ++nf) {
      bf16x8 wh = *(const bf16x8*)(ph_[nf] + kt * 32);
      bf16x8 wl = *(const bf16x8*)(pl_[nf] + kt * 32);
      acc2[nf] = __builtin_amdgcn_mfma_f32_16x16x32_bf16(ah, wh, acc2[nf], 0, 0, 0);
      acc2[nf] = __builtin_amdgcn_mfma_f32_16x16x32_bf16(ah, wl, acc2[nf], 0, 0, 0);
      acc2[nf] = __builtin_amdgcn_mfma_f32_16x16x32_bf16(al, wh, acc2[nf], 0, 0, 0);
    }
  }
#pragma unroll
  for (int nf = 0; nf < 8; ++nf) {
    int col = n0 + nf * 16 + arow;
    float bb = bc[col];
#pragma unroll
    for (int rr = 0; rr < 4; ++rr)
      Hp1[(size_t)(r0 + h * 4 + rr) * G4 + col] = acc2[nf][rr] + bb;
  }
}

// ---------------------------------------------------------------------------
// pool_mfma v3: barrier-free. Block = (scene, i-pair, n-half); 4 waves split N.
// Each lane generates its own A-fragment values in registers (A layout:
// row=lane&15, k=(lane>>4)*8+q), B direct from L2-resident W2T. No LDS
// staging, no barriers in the k-loop -> loads pipeline across iterations.
// ---------------------------------------------------------------------------
__global__ __launch_bounds__(256) void pool_mfma(
    const float* __restrict__ curr_pos, const float* __restrict__ Hp1,
    const float* __restrict__ Wc,
    const unsigned short* __restrict__ W2T, const float* __restrict__ b_p2,
    float* __restrict__ pool_h) {
  __shared__ float psx[NP], psy[NP];
  __shared__ __align__(16) float wc0[G4], wc1[G4];
  int t = threadIdx.x;
  int b = blockIdx.x;              // 768 = 32 scenes * 12 ipairs * 2 nhalf
  int s = b / 24, rem = b % 24;
  int ip = rem >> 1, nh = rem & 1;
  if (t < NP) {
    psx[t] = curr_pos[(s * NP + t) * 2];
    psy[t] = curr_pos[(s * NP + t) * 2 + 1];
  }
  for (int i = t; i < G4; i += 256) { wc0[i] = Wc[i]; wc1[i] = Wc[G4 + i]; }
  __syncthreads();

  int lane = t & 63, wn = t >> 6;
  int arow = lane & 15, ak = (lane >> 4) * 8;
  int n0 = nh * 512 + wn * 128;

  const float* hp[3];
  float rx[3], ry[3];
#pragma unroll
  for (int f = 0; f < 3; ++f) {
    int m = f * 16 + arow;
    int j = m % 24, g = m / 24;
    hp[f] = Hp1 + (size_t)(s * NP + j) * G4 + ak;
    rx[f] = psx[j] - psx[ip * 2 + g];
    ry[f] = psy[j] - psy[ip * 2 + g];
  }
  const unsigned short* bp[8];
#pragma unroll
  for (int nf = 0; nf < 8; ++nf)
    bp[nf] = W2T + (size_t)(n0 + nf * 16 + arow) * G4 + ak;

  f32x4 acc[3][8];
#pragma unroll
  for (int f = 0; f < 3; ++f)
#pragma unroll
    for (int nf = 0; nf < 8; ++nf) acc[f][nf] = (f32x4){0.f, 0.f, 0.f, 0.f};

#pragma unroll 2
  for (int kt = 0; kt < 16; ++kt) {
    int k0 = kt * 32;
    bf16x8 bfr[8];
#pragma unroll
    for (int nf = 0; nf < 8; ++nf) bfr[nf] = *(const bf16x8*)(bp[nf] + k0);
    float4 wa = *(const float4*)&wc0[k0 + ak];
    float4 wb = *(const float4*)&wc0[k0 + ak + 4];
    float4 va = *(const float4*)&wc1[k0 + ak];
    float4 vb = *(const float4*)&wc1[k0 + ak + 4];
    bf16x8 af[3];
#pragma unroll
    for (int f = 0; f < 3; ++f) {
      float4 h0 = *(const float4*)(hp[f] + k0);
      float4 h1 = *(const float4*)(hp[f] + k0 + 4);
      float rxf = rx[f], ryf = ry[f];
      af[f][0] = (__bf16)fmaxf(h0.x + rxf * wa.x + ryf * va.x, 0.f);
      af[f][1] = (__bf16)fmaxf(h0.y + rxf * wa.y + ryf * va.y, 0.f);
      af[f][2] = (__bf16)fmaxf(h0.z + rxf * wa.z + ryf * va.z, 0.f);
      af[f][3] = (__bf16)fmaxf(h0.w + rxf * wa.w + ryf * va.w, 0.f);
      af[f][4] = (__bf16)fmaxf(h1.x + rxf * wb.x + ryf * vb.x, 0.f);
      af[f][5] = (__bf16)fmaxf(h1.y + rxf * wb.y + ryf * vb.y, 0.f);
      af[f][6] = (__bf16)fmaxf(h1.z + rxf * wb.z + ryf * vb.z, 0.f);
      af[f][7] = (__bf16)fmaxf(h1.w + rxf * wb.w + ryf * vb.w, 0.f);
    }
#pragma unroll
    for (int nf = 0; nf < 8; ++nf)
#pragma unroll
      for (int f = 0; f < 3; ++f)
        acc[f][nf] = __builtin_amdgcn_mfma_f32_16x16x32_bf16(af[f], bfr[nf], acc[f][nf], 0, 0, 0);
  }

  // epilogue: max over j per ped group. frag rows: f0=g0 j0-15,
  // f1 lo=g0 j16-23 / hi=g1 j0-7, f2=g1 j8-23. C: row=(lane>>4)*4+reg, col=lane&15.
  int h = lane >> 4;
  int iA = s * NP + ip * 2;
#pragma unroll
  for (int nf = 0; nf < 8; ++nf) {
    f32x4 a0 = acc[0][nf], a1 = acc[1][nf], a2 = acc[2][nf];
    float v0 = fmaxf(fmaxf(a0[0], a0[1]), fmaxf(a0[2], a0[3]));
    float v1 = fmaxf(fmaxf(a1[0], a1[1]), fmaxf(a1[2], a1[3]));
    float v2 = fmaxf(fmaxf(a2[0], a2[1]), fmaxf(a2[2], a2[3]));
    v0 = fmaxf(v0, __shfl_xor(v0, 16));
    v1 = fmaxf(v1, __shfl_xor(v1, 16));
    v2 = fmaxf(v2, __shfl_xor(v2, 16));
    float xx = (h < 2) ? fmaxf(v0, v1) : v0;    // g0 = f0 all + f1 lo
    xx = fmaxf(xx, __shfl_xor(xx, 32));
    float yy = (h >= 2) ? fmaxf(v2, v1) : v2;   // g1 = f1 hi + f2 all
    yy = fmaxf(yy, __shfl_xor(yy, 32));
    int col = n0 + nf * 16 + (lane & 15);
    float bb = b_p2[col];
    xx = fmaxf(xx + bb, 0.f);
    yy = fmaxf(yy + bb, 0.f);
    if (h == 0) pool_h[(size_t)iA * BNKD + col] = xx;
    if (h == 1) pool_h[((size_t)iA + 1) * BNKD + col] = yy;
  }
}

// ---------------------------------------------------------------------------
// mlp1_fused: stage1 mh_tile = relu([hn|ph] @ W_m1 + b_m1) (32x128, regs),
// stage2 hacc += mh_tile @ W_m2[n0:n0+128, :] via bf16 hi+lo MFMA + atomicAdd.
// ---------------------------------------------------------------------------
__global__ __launch_bounds__(256) void mlp1_fused(
    const float* __restrict__ hn, const float* __restrict__ ph,
    const unsigned short* __restrict__ W1T, const float* __restrict__ b_m1,
    const unsigned short* __restrict__ WmT, float* __restrict__ hacc) {
  __shared__ __align__(16) float Pl[32][132];
  int t = threadIdx.x, b = blockIdx.x;   // 192 = 24 mt * 8 nt
  int mt = b >> 3, nt = b & 7;
  int r0 = mt * 32, n0 = nt * 128;
  int lane = t & 63, wid = t >> 6, wm = wid >> 1, wn = wid & 1;
  int arow = lane & 15, ak = (lane >> 4) * 8;
  int h = lane >> 4;

  f32x4 acc0[4];
#pragma unroll
  for (int nf = 0; nf < 4; ++nf) acc0[nf] = (f32x4){0.f, 0.f, 0.f, 0.f};
  int mrow = r0 + wm * 16 + arow;
  const unsigned short* bp[4];
#pragma unroll
  for (int nf = 0; nf < 4; ++nf)
    bp[nf] = W1T + (size_t)(n0 + wn * 64 + nf * 16 + arow) * KM1 + ak;
  const float* arow_h = hn + (size_t)mrow * HD;
  const float* arow_p = ph + (size_t)mrow * BNKD - HD;  // biased so [kg] works

  for (int kt = 0; kt < 36; ++kt) {
    int kg = kt * 32 + ak;
    const float* src = (kg < HD) ? arow_h : arow_p;
    float4 v0 = *(const float4*)&src[kg];
    float4 v1 = *(const float4*)&src[kg + 4];
    u16x8 ua;
    ua[0] = f2bf(v0.x); ua[1] = f2bf(v0.y); ua[2] = f2bf(v0.z); ua[3] = f2bf(v0.w);
    ua[4] = f2bf(v1.x); ua[5] = f2bf(v1.y); ua[6] = f2bf(v1.z); ua[7] = f2bf(v1.w);
    bf16x8 a = __builtin_bit_cast(bf16x8, ua);
#pragma unroll
    for (int nf = 0; nf < 4; ++nf) {
      bf16x8 bb = *(const bf16x8*)(bp[nf] + kt * 32);
      acc0[nf] = __builtin_amdgcn_mfma_f32_16x16x32_bf16(a, bb, acc0[nf], 0, 0, 0);
    }
  }

  // P = relu(acc0 + b_m1) -> LDS (fp32)
#pragma unroll
  for (int nf = 0; nf < 4; ++nf) {
    int colp = wn * 64 + nf * 16 + arow;
    float bb = b_m1[n0 + colp];
#pragma unroll
    for (int rr = 0; rr < 4; ++rr)
      Pl[wm * 16 + h * 4 + rr][colp] = fmaxf(acc0[nf][rr] + bb, 0.f);
  }
  __syncthreads();

  // stage 2: (32x128 P-tile) @ WmT[:, n0:n0+128]^T -> 32x128 partial of h
  f32x4 acc2[4];
#pragma unroll
  for (int nf = 0; nf < 4; ++nf) acc2[nf] = (f32x4){0.f, 0.f, 0.f, 0.f};
  const unsigned short* b2p[4];
#pragma unroll
  for (int nf = 0; nf < 4; ++nf)
    b2p[nf] = WmT + (size_t)(wn * 64 + nf * 16 + arow) * BNKD + n0 + ak;
  const float* prow = &Pl[wm * 16 + arow][0];

#pragma unroll
  for (int k2 = 0; k2 < 4; ++k2) {
    u16x8 uh, ul;
#pragma unroll
    for (int q = 0; q < 8; ++q) {
      float vv = prow[k2 * 32 + ak + q];
      unsigned short hh = f2bf(vv);
      uh[q] = hh;
      ul[q] = f2bf(vv - bf2f(hh));
    }
    bf16x8 ahi = __builtin_bit_cast(bf16x8, uh);
    bf16x8 alo = __builtin_bit_cast(bf16x8, ul);
#pragma unroll
    for (int nf = 0; nf < 4; ++nf) {
      bf16x8 bb = *(const bf16x8*)(b2p[nf] + k2 * 32);
      acc2[nf] = __builtin_amdgcn_mfma_f32_16x16x32_bf16(ahi, bb, acc2[nf], 0, 0, 0);
      acc2[nf] = __builtin_amdgcn_mfma_f32_16x16x32_bf16(alo, bb, acc2[nf], 0, 0, 0);
    }
  }
#pragma unroll
  for (int nf = 0; nf < 4; ++nf)
#pragma unroll
    for (int rr = 0; rr < 4; ++rr)
      atomicAdd(&hacc[(size_t)(r0 + wm * 16 + h * 4 + rr) * HD + wn * 64 + nf * 16 + arow],
                acc2[nf][rr]);
}

// ---------------------------------------------------------------------------
// final: h_fin = relu(hacc)
// ---------------------------------------------------------------------------
__global__ void final_h(const float* __restrict__ hacc, float* __restrict__ out) {
  int i = blockIdx.x * 256 + threadIdx.x;
  if (i < NB * HD) out[i] = fmaxf(hacc[i], 0.f);
}

// ---------------------------------------------------------------------------
extern "C" void kernel_launch(void* const* d_in, const int* in_sizes, int n_in,
                              void* d_out, int out_size, void* d_ws, size_t ws_size,
                              hipStream_t stream) {
  const float* last_pos     = (const float*)d_in[0];
  const float* last_pos_rel = (const float*)d_in[1];
  const float* h0   = (const float*)d_in[2];
  const float* c0   = (const float*)d_in[3];
  const float* W_se = (const float*)d_in[5];
  const float* b_se = (const float*)d_in[6];
  const float* W_ih = (const float*)d_in[7];
  const float* b_ih = (const float*)d_in[8];
  const float* W_hh = (const float*)d_in[9];
  const float* b_hh = (const float*)d_in[10];
  const float* W_hp = (const float*)d_in[11];
  const float* b_hp = (const float*)d_in[12];
  const float* W_pse = (const float*)d_in[13];
  const float* b_pse = (const float*)d_in[14];
  const float* W_p1 = (const float*)d_in[15];
  const float* b_p1 = (const float*)d_in[16];
  const float* W_p2 = (const float*)d_in[17];
  const float* b_p2 = (const float*)d_in[18];
  const float* W_m1 = (const float*)d_in[19];
  const float* b_m1 = (const float*)d_in[20];
  const float* W_m2 = (const float*)d_in[21];
  const float* b_m2 = (const float*)d_in[22];

  float* ws = (float*)d_ws;
  float* hacc[2]  = { ws,           ws + 98304 };
  float* ccar[2]  = { ws + 196608,  ws + 294912 };
  float* din[2]   = { ws + 393216,  ws + 442368 };
  float* lposb[2] = { ws + 491520,  ws + 493056 };
  float* hn   = ws + 494592;
  float* Hp1  = ws + 592896;
  float* ph   = ws + 986112;
  float* Wc   = ws + 1772544;
  float* bc   = ws + 1773568;
  unsigned short* W2T = (unsigned short*)(ws + 1774080);     // 1024x512
  unsigned short* W1T = (unsigned short*)(ws + 2036224);     // 1024x1152
  unsigned short* WmT = (unsigned short*)(ws + 2626048);     // 128x1024
  unsigned short* WgT_hi  = (unsigned short*)(ws + 2691584); // 512x192
  unsigned short* WgT_lo  = (unsigned short*)(ws + 2740736);
  unsigned short* Wp1T_hi = (unsigned short*)(ws + 2789888); // 512x128
  unsigned short* Wp1T_lo = (unsigned short*)(ws + 2822656);
  float* bg = ws + 2855424;

  float* pred = (float*)d_out;

  init_kernel<<<128, 256, 0, stream>>>(last_pos, last_pos_rel, c0,
                                       W_se, b_se, W_pse, b_pse, W_p1, b_p1,
                                       W_p2, W_m1, W_m2, W_ih, W_hh, b_ih, b_hh,
                                       ccar[0], din[0], lposb[0],
                                       Wc, bc, W2T, W1T, WmT,
                                       WgT_hi, WgT_lo, Wp1T_hi, Wp1T_lo, bg);

  for (int t = 0; t < TSTEPS; ++t) {
    int a = t & 1, b = (t + 1) & 1;
    step_a_mfma<<<NB / 16, 256, 0, stream>>>(
        t == 0 ? h0 : hacc[a], ccar[a], din[a], lposb[a],
        WgT_hi, WgT_lo, bg, Wp1T_hi, Wp1T_lo, bc,
        W_hp, b_hp, W_se, b_se, b_m2,
        hn, ccar[b], din[b], lposb[b], Hp1, pred + t * NB * 2,
        hacc[b], t == 0 ? 0 : 1);
    pool_mfma<<<NS * 24, 256, 0, stream>>>(lposb[b], Hp1, Wc, W2T, b_p2, ph);
    mlp1_fused<<<192, 256, 0, stream>>>(hn, ph, W1T, b_m1, WmT, hacc[b]);
  }

  final_h<<<384, 256, 0, stream>>>(hacc[0], (float*)d_out + TSTEPS * NB * 2);
}

// Round 6
// 1468.042 us; speedup vs baseline: 1.2857x; 1.2857x over previous
//
#include <hip/hip_runtime.h>
#include <math.h>

// Problem constants (uniform scenes per reference)
#define NB 768      // batch = S*P
#define NS 32       // scenes
#define NP 24       // peds/scene
#define ED 64       // embedding dim E
#define HD 128      // hidden H
#define G4 512      // 4*H
#define BNKD 1024   // bottleneck
#define KM1 1152    // H + BNK
#define TSTEPS 12
#define AR 4        // rows per step_a block
#define PADW 522    // pool Y-tile row pitch in shorts (odd word count 261)

typedef __bf16 bf16x8 __attribute__((ext_vector_type(8)));
typedef float f32x4 __attribute__((ext_vector_type(4)));
typedef unsigned short u16x8 __attribute__((ext_vector_type(8)));

__device__ __forceinline__ unsigned short f2bf(float f) {
  unsigned u = __float_as_uint(f);
  u = (u + 0x7FFFu + ((u >> 16) & 1u)) >> 16;   // RNE
  return (unsigned short)u;
}
__device__ __forceinline__ unsigned pack2bf(float a, float b) {
  return (unsigned)f2bf(a) | ((unsigned)f2bf(b) << 16);
}
__device__ __forceinline__ float bf2f(unsigned short h) {
  return __uint_as_float(((unsigned)h) << 16);
}

// ---------------------------------------------------------------------------
// init: carries, dec_in0, folded pool-L1 weights (Wc = W_pse@W_p1[:64], bc),
// bf16-transposed W2T[n][k]=W_p2[k][n], W1T[n][k]=W_m1[k][n], WmT[n][k]=W_m2[k][n]
// ---------------------------------------------------------------------------
__global__ void init_kernel(const float* __restrict__ last_pos,
                            const float* __restrict__ last_pos_rel,
                            const float* __restrict__ c0,
                            const float* __restrict__ W_se,
                            const float* __restrict__ b_se,
                            const float* __restrict__ W_pse,
                            const float* __restrict__ b_pse,
                            const float* __restrict__ W_p1,
                            const float* __restrict__ b_p1,
                            const float* __restrict__ W_p2,
                            const float* __restrict__ W_m1,
                            const float* __restrict__ W_m2,
                            float* __restrict__ ccar,
                            float* __restrict__ din, float* __restrict__ lpos,
                            float* __restrict__ Wc, float* __restrict__ bc,
                            unsigned short* __restrict__ W2T,
                            unsigned short* __restrict__ W1T,
                            unsigned short* __restrict__ WmT) {
  int stride = gridDim.x * blockDim.x;
  int idx0 = blockIdx.x * blockDim.x + threadIdx.x;
  for (int i = idx0; i < NB * HD; i += stride) ccar[i] = c0[i];
  for (int i = idx0; i < NB * 2; i += stride) lpos[i] = last_pos[i];
  for (int i = idx0; i < NB * ED; i += stride) {
    int r = i >> 6, e = i & 63;
    din[i] = b_se[e] + last_pos_rel[2 * r] * W_se[e]
                     + last_pos_rel[2 * r + 1] * W_se[ED + e];
  }
  for (int n = idx0; n < G4; n += stride) {
    float w0 = 0.f, w1 = 0.f, bb = b_p1[n];
    for (int e = 0; e < ED; ++e) {
      float wp = W_p1[e * G4 + n];
      w0 += W_pse[e] * wp;
      w1 += W_pse[ED + e] * wp;
      bb += b_pse[e] * wp;
    }
    Wc[n] = w0; Wc[G4 + n] = w1; bc[n] = bb;
  }
  // W2T: 1024 n x 512 k bf16
  for (int idx = idx0; idx < 1024 * 64; idx += stride) {
    int n = idx & 1023, k0 = (idx >> 10) << 3;
    unsigned pk0 = pack2bf(W_p2[(k0 + 0) * BNKD + n], W_p2[(k0 + 1) * BNKD + n]);
    unsigned pk1 = pack2bf(W_p2[(k0 + 2) * BNKD + n], W_p2[(k0 + 3) * BNKD + n]);
    unsigned pk2 = pack2bf(W_p2[(k0 + 4) * BNKD + n], W_p2[(k0 + 5) * BNKD + n]);
    unsigned pk3 = pack2bf(W_p2[(k0 + 6) * BNKD + n], W_p2[(k0 + 7) * BNKD + n]);
    *(uint4*)&W2T[n * G4 + k0] = make_uint4(pk0, pk1, pk2, pk3);
  }
  // W1T: 1024 n x 1152 k bf16
  for (int idx = idx0; idx < 1024 * 144; idx += stride) {
    int n = idx & 1023, k0 = (idx >> 10) << 3;
    unsigned pk0 = pack2bf(W_m1[(k0 + 0) * BNKD + n], W_m1[(k0 + 1) * BNKD + n]);
    unsigned pk1 = pack2bf(W_m1[(k0 + 2) * BNKD + n], W_m1[(k0 + 3) * BNKD + n]);
    unsigned pk2 = pack2bf(W_m1[(k0 + 4) * BNKD + n], W_m1[(k0 + 5) * BNKD + n]);
    unsigned pk3 = pack2bf(W_m1[(k0 + 6) * BNKD + n], W_m1[(k0 + 7) * BNKD + n]);
    *(uint4*)&W1T[n * KM1 + k0] = make_uint4(pk0, pk1, pk2, pk3);
  }
  // WmT: 128 n x 1024 k bf16   (W_m2 is [1024][128])
  for (int idx = idx0; idx < 128 * 128; idx += stride) {
    int n = idx & 127, k0 = (idx >> 7) << 3;
    unsigned pk0 = pack2bf(W_m2[(k0 + 0) * HD + n], W_m2[(k0 + 1) * HD + n]);
    unsigned pk1 = pack2bf(W_m2[(k0 + 2) * HD + n], W_m2[(k0 + 3) * HD + n]);
    unsigned pk2 = pack2bf(W_m2[(k0 + 4) * HD + n], W_m2[(k0 + 5) * HD + n]);
    unsigned pk3 = pack2bf(W_m2[(k0 + 6) * HD + n], W_m2[(k0 + 7) * HD + n]);
    *(uint4*)&WmT[n * BNKD + k0] = make_uint4(pk0, pk1, pk2, pk3);
  }
}

// ---------------------------------------------------------------------------
// step A (R4 version, measured faster than MFMA variant at grid 48):
// LSTM cell (h read = relu(hacc_prev) unless first step) + rel/curr pos
// + dec_in_next + Hp1 = h_new @ W_p1[64:] + bc + hacc_next init = b_m2.
// 4 rows/block, grid 192.
// ---------------------------------------------------------------------------
__global__ __launch_bounds__(256) void step_a(
    const float* __restrict__ hprev, const float* __restrict__ cprev,
    const float* __restrict__ din, const float* __restrict__ lpos_in,
    const float* __restrict__ W_ih, const float* __restrict__ b_ih,
    const float* __restrict__ W_hh, const float* __restrict__ b_hh,
    const float* __restrict__ W_hp, const float* __restrict__ b_hp,
    const float* __restrict__ W_se, const float* __restrict__ b_se,
    const float* __restrict__ W_p1, const float* __restrict__ bc,
    const float* __restrict__ b_m2,
    float* __restrict__ hn, float* __restrict__ cnext,
    float* __restrict__ dnext, float* __restrict__ lpos_out,
    float* __restrict__ Hp1, float* __restrict__ pred_out,
    float* __restrict__ hacc_next, int relu_in) {
  __shared__ float x[AR][192];   // [din(64) | h(128)]
  __shared__ float gg[AR][G4];
  __shared__ float hl[AR][HD];
  __shared__ float rp[AR][2];
  int t = threadIdx.x;
  int r0 = blockIdx.x * AR;

  for (int i = t; i < AR * ED; i += 256) { int r = i >> 6, k = i & 63; x[r][k] = din[(r0 + r) * ED + k]; }
  for (int i = t; i < AR * HD; i += 256) {
    int r = i >> 7, k = i & 127;
    float v = hprev[(r0 + r) * HD + k];
    if (relu_in) v = fmaxf(v, 0.f);
    x[r][ED + k] = v;
    hacc_next[(r0 + r) * HD + k] = b_m2[k];   // bias-init mlp2 accumulator
  }
  __syncthreads();

  float acc[AR][2];
#pragma unroll
  for (int r = 0; r < AR; ++r) { acc[r][0] = b_ih[t] + b_hh[t]; acc[r][1] = b_ih[t + 256] + b_hh[t + 256]; }
  for (int k = 0; k < ED; ++k) {
    float w0 = W_ih[k * G4 + t], w1 = W_ih[k * G4 + t + 256];
#pragma unroll
    for (int r = 0; r < AR; ++r) { float a = x[r][k]; acc[r][0] += a * w0; acc[r][1] += a * w1; }
  }
  for (int k = 0; k < HD; ++k) {
    float w0 = W_hh[k * G4 + t], w1 = W_hh[k * G4 + t + 256];
#pragma unroll
    for (int r = 0; r < AR; ++r) { float a = x[r][ED + k]; acc[r][0] += a * w0; acc[r][1] += a * w1; }
  }
#pragma unroll
  for (int r = 0; r < AR; ++r) { gg[r][t] = acc[r][0]; gg[r][t + 256] = acc[r][1]; }
  __syncthreads();

  for (int i = t; i < AR * HD; i += 256) {
    int r = i >> 7, k = i & 127;
    float ig = gg[r][k], fg = gg[r][HD + k], gz = gg[r][2 * HD + k], og = gg[r][3 * HD + k];
    float si = 1.f / (1.f + expf(-ig));
    float sf = 1.f / (1.f + expf(-fg));
    float so = 1.f / (1.f + expf(-og));
    float gt = tanhf(gz);
    float c = sf * cprev[(r0 + r) * HD + k] + si * gt;
    float h = so * tanhf(c);
    cnext[(r0 + r) * HD + k] = c;
    hn[(r0 + r) * HD + k] = h;
    hl[r][k] = h;
  }
  __syncthreads();

  if (t < AR * 2) {
    int r = t >> 1, d = t & 1;
    float s = b_hp[d];
    for (int k = 0; k < HD; ++k) s += hl[r][k] * W_hp[k * 2 + d];
    rp[r][d] = s;
    pred_out[(r0 + r) * 2 + d] = s;
    lpos_out[(r0 + r) * 2 + d] = s + lpos_in[(r0 + r) * 2 + d];
  }
  __syncthreads();

  for (int i = t; i < AR * ED; i += 256) {
    int r = i >> 6, e = i & 63;
    dnext[(r0 + r) * ED + e] = b_se[e] + rp[r][0] * W_se[e] + rp[r][1] * W_se[ED + e];
  }

  // Hp1 = h_new @ W_p1[64:192] + bc   (bc folded here)
  float bc0 = bc[t], bc1 = bc[t + 256];
  float acc2[AR][2];
#pragma unroll
  for (int r = 0; r < AR; ++r) { acc2[r][0] = bc0; acc2[r][1] = bc1; }
  for (int k = 0; k < HD; ++k) {
    float w0 = W_p1[(ED + k) * G4 + t], w1 = W_p1[(ED + k) * G4 + t + 256];
#pragma unroll
    for (int r = 0; r < AR; ++r) { float a = hl[r][k]; acc2[r][0] += a * w0; acc2[r][1] += a * w1; }
  }
#pragma unroll
  for (int r = 0; r < AR; ++r) {
    Hp1[(r0 + r) * G4 + t] = acc2[r][0];
    Hp1[(r0 + r) * G4 + t + 256] = acc2[r][1];
  }
}

// ---------------------------------------------------------------------------
// pool_mfma v4: block = (scene, i-pair, n-half). M=48 (2 peds x 24 j), N=512.
// Phase 1: generate FULL Y[48][512] bf16 tile into LDS (one barrier total).
// Phase 2: barrier-free k-loop: A via ds_read_b128, B direct from L2-resident
// W2T, 24 MFMA/k-step/wave. Row pitch 522 shorts (odd words) -> conflict-free.
// ---------------------------------------------------------------------------
__global__ __launch_bounds__(256, 3) void pool_mfma(
    const float* __restrict__ curr_pos, const float* __restrict__ Hp1,
    const float* __restrict__ Wc,
    const unsigned short* __restrict__ W2T, const float* __restrict__ b_p2,
    float* __restrict__ pool_h) {
  __shared__ __align__(16) unsigned short Al[48 * PADW];   // 50112 B
  __shared__ float psx[NP], psy[NP];
  int t = threadIdx.x;
  int b = blockIdx.x;              // 768 = 32 scenes * 12 ipairs * 2 nhalf
  int s = b / 24, rem = b % 24;
  int ip = rem >> 1, nh = rem & 1;
  if (t < NP) {
    psx[t] = curr_pos[(s * NP + t) * 2];
    psy[t] = curr_pos[(s * NP + t) * 2 + 1];
  }
  __syncthreads();

  // ---- Phase 1: Y[m][k] = relu(Hp1[j][k] + rx*Wc[k] + ry*Wc[512+k]) ----
  {
    int mq = t >> 4;            // 0..15
    int q2 = (t & 15) * 2;      // k-pair base
#pragma unroll
    for (int p = 0; p < 3; ++p) {
      int m = p * 16 + mq;
      int j = m % 24, g = m / 24;
      float rx = psx[j] - psx[ip * 2 + g];
      float ry = psy[j] - psy[ip * 2 + g];
      const float* hr = Hp1 + (size_t)(s * NP + j) * G4;
#pragma unroll 4
      for (int c = 0; c < 16; ++c) {
        int k = c * 32 + q2;
        float2 hv = *(const float2*)&hr[k];
        float2 wx = *(const float2*)&Wc[k];
        float2 wy = *(const float2*)&Wc[G4 + k];
        float v0 = fmaxf(hv.x + rx * wx.x + ry * wy.x, 0.f);
        float v1 = fmaxf(hv.y + rx * wx.y + ry * wy.y, 0.f);
        *(unsigned*)&Al[m * PADW + k] = pack2bf(v0, v1);
      }
    }
  }
  __syncthreads();

  // ---- Phase 2: barrier-free MFMA loop ----
  int lane = t & 63, wn = t >> 6;
  int arow = lane & 15, ak = (lane >> 4) * 8;
  int n0 = nh * 512 + wn * 128;

  const unsigned short* bp[8];
#pragma unroll
  for (int nf = 0; nf < 8; ++nf)
    bp[nf] = W2T + (size_t)(n0 + nf * 16 + arow) * G4 + ak;
  int aoff[3];
#pragma unroll
  for (int f = 0; f < 3; ++f) aoff[f] = (f * 16 + arow) * PADW + ak;

  f32x4 acc[3][8];
#pragma unroll
  for (int f = 0; f < 3; ++f)
#pragma unroll
    for (int nf = 0; nf < 8; ++nf) acc[f][nf] = (f32x4){0.f, 0.f, 0.f, 0.f};

#pragma unroll 2
  for (int kt = 0; kt < 16; ++kt) {
    int k0 = kt * 32;
    bf16x8 bfr[8];
#pragma unroll
    for (int nf = 0; nf < 8; ++nf) bfr[nf] = *(const bf16x8*)(bp[nf] + k0);
    bf16x8 af[3];
#pragma unroll
    for (int f = 0; f < 3; ++f) af[f] = *(const bf16x8*)&Al[aoff[f] + k0];
#pragma unroll
    for (int nf = 0; nf < 8; ++nf)
#pragma unroll
      for (int f = 0; f < 3; ++f)
        acc[f][nf] = __builtin_amdgcn_mfma_f32_16x16x32_bf16(af[f], bfr[nf], acc[f][nf], 0, 0, 0);
  }

  // epilogue: max over j per ped group. frag rows: f0=g0 j0-15,
  // f1 lo=g0 j16-23 / hi=g1 j0-7, f2=g1 j8-23. C: row=(lane>>4)*4+reg, col=lane&15.
  int h = lane >> 4;
  int iA = s * NP + ip * 2;
#pragma unroll
  for (int nf = 0; nf < 8; ++nf) {
    f32x4 a0 = acc[0][nf], a1 = acc[1][nf], a2 = acc[2][nf];
    float v0 = fmaxf(fmaxf(a0[0], a0[1]), fmaxf(a0[2], a0[3]));
    float v1 = fmaxf(fmaxf(a1[0], a1[1]), fmaxf(a1[2], a1[3]));
    float v2 = fmaxf(fmaxf(a2[0], a2[1]), fmaxf(a2[2], a2[3]));
    v0 = fmaxf(v0, __shfl_xor(v0, 16));
    v1 = fmaxf(v1, __shfl_xor(v1, 16));
    v2 = fmaxf(v2, __shfl_xor(v2, 16));
    float xx = (h < 2) ? fmaxf(v0, v1) : v0;    // g0 = f0 all + f1 lo
    xx = fmaxf(xx, __shfl_xor(xx, 32));
    float yy = (h >= 2) ? fmaxf(v2, v1) : v2;   // g1 = f1 hi + f2 all
    yy = fmaxf(yy, __shfl_xor(yy, 32));
    int col = n0 + nf * 16 + (lane & 15);
    float bb = b_p2[col];
    xx = fmaxf(xx + bb, 0.f);
    yy = fmaxf(yy + bb, 0.f);
    if (h == 0) pool_h[(size_t)iA * BNKD + col] = xx;
    if (h == 1) pool_h[((size_t)iA + 1) * BNKD + col] = yy;
  }
}

// ---------------------------------------------------------------------------
// mlp1_fused: stage1 mh_tile = relu([hn|ph] @ W_m1 + b_m1) (32x128, regs),
// stage2 hacc += mh_tile @ W_m2[n0:n0+128, :] via bf16 hi+lo MFMA + atomicAdd.
// ---------------------------------------------------------------------------
__global__ __launch_bounds__(256) void mlp1_fused(
    const float* __restrict__ hn, const float* __restrict__ ph,
    const unsigned short* __restrict__ W1T, const float* __restrict__ b_m1,
    const unsigned short* __restrict__ WmT, float* __restrict__ hacc) {
  __shared__ __align__(16) float Pl[32][132];
  int t = threadIdx.x, b = blockIdx.x;   // 192 = 24 mt * 8 nt
  int mt = b >> 3, nt = b & 7;
  int r0 = mt * 32, n0 = nt * 128;
  int lane = t & 63, wid = t >> 6, wm = wid >> 1, wn = wid & 1;
  int arow = lane & 15, ak = (lane >> 4) * 8;
  int h = lane >> 4;

  f32x4 acc0[4];
#pragma unroll
  for (int nf = 0; nf < 4; ++nf) acc0[nf] = (f32x4){0.f, 0.f, 0.f, 0.f};
  int mrow = r0 + wm * 16 + arow;
  const unsigned short* bp[4];
#pragma unroll
  for (int nf = 0; nf < 4; ++nf)
    bp[nf] = W1T + (size_t)(n0 + wn * 64 + nf * 16 + arow) * KM1 + ak;
  const float* arow_h = hn + (size_t)mrow * HD;
  const float* arow_p = ph + (size_t)mrow * BNKD - HD;  // biased so [kg] works

  for (int kt = 0; kt < 36; ++kt) {
    int kg = kt * 32 + ak;
    const float* src = (kg < HD) ? arow_h : arow_p;
    float4 v0 = *(const float4*)&src[kg];
    float4 v1 = *(const float4*)&src[kg + 4];
    u16x8 ua;
    ua[0] = f2bf(v0.x); ua[1] = f2bf(v0.y); ua[2] = f2bf(v0.z); ua[3] = f2bf(v0.w);
    ua[4] = f2bf(v1.x); ua[5] = f2bf(v1.y); ua[6] = f2bf(v1.z); ua[7] = f2bf(v1.w);
    bf16x8 a = __builtin_bit_cast(bf16x8, ua);
#pragma unroll
    for (int nf = 0; nf < 4; ++nf) {
      bf16x8 bb = *(const bf16x8*)(bp[nf] + kt * 32);
      acc0[nf] = __builtin_amdgcn_mfma_f32_16x16x32_bf16(a, bb, acc0[nf], 0, 0, 0);
    }
  }

  // P = relu(acc0 + b_m1) -> LDS (fp32)
#pragma unroll
  for (int nf = 0; nf < 4; ++nf) {
    int colp = wn * 64 + nf * 16 + arow;
    float bb = b_m1[n0 + colp];
#pragma unroll
    for (int rr = 0; rr < 4; ++rr)
      Pl[wm * 16 + h * 4 + rr][colp] = fmaxf(acc0[nf][rr] + bb, 0.f);
  }
  __syncthreads();

  // stage 2: (32x128 P-tile) @ WmT[:, n0:n0+128]^T -> 32x128 partial of h
  f32x4 acc2[4];
#pragma unroll
  for (int nf = 0; nf < 4; ++nf) acc2[nf] = (f32x4){0.f, 0.f, 0.f, 0.f};
  const unsigned short* b2p[4];
#pragma unroll
  for (int nf = 0; nf < 4; ++nf)
    b2p[nf] = WmT + (size_t)(wn * 64 + nf * 16 + arow) * BNKD + n0 + ak;
  const float* prow = &Pl[wm * 16 + arow][0];

#pragma unroll
  for (int k2 = 0; k2 < 4; ++k2) {
    u16x8 uh, ul;
#pragma unroll
    for (int q = 0; q < 8; ++q) {
      float vv = prow[k2 * 32 + ak + q];
      unsigned short hh = f2bf(vv);
      uh[q] = hh;
      ul[q] = f2bf(vv - bf2f(hh));
    }
    bf16x8 ahi = __builtin_bit_cast(bf16x8, uh);
    bf16x8 alo = __builtin_bit_cast(bf16x8, ul);
#pragma unroll
    for (int nf = 0; nf < 4; ++nf) {
      bf16x8 bb = *(const bf16x8*)(b2p[nf] + k2 * 32);
      acc2[nf] = __builtin_amdgcn_mfma_f32_16x16x32_bf16(ahi, bb, acc2[nf], 0, 0, 0);
      acc2[nf] = __builtin_amdgcn_mfma_f32_16x16x32_bf16(alo, bb, acc2[nf], 0, 0, 0);
    }
  }
#pragma unroll
  for (int nf = 0; nf < 4; ++nf)
#pragma unroll
    for (int rr = 0; rr < 4; ++rr)
      atomicAdd(&hacc[(size_t)(r0 + wm * 16 + h * 4 + rr) * HD + wn * 64 + nf * 16 + arow],
                acc2[nf][rr]);
}

// ---------------------------------------------------------------------------
// final: h_fin = relu(hacc)
// ---------------------------------------------------------------------------
__global__ void final_h(const float* __restrict__ hacc, float* __restrict__ out) {
  int i = blockIdx.x * 256 + threadIdx.x;
  if (i < NB * HD) out[i] = fmaxf(hacc[i], 0.f);
}

// ---------------------------------------------------------------------------
extern "C" void kernel_launch(void* const* d_in, const int* in_sizes, int n_in,
                              void* d_out, int out_size, void* d_ws, size_t ws_size,
                              hipStream_t stream) {
  const float* last_pos     = (const float*)d_in[0];
  const float* last_pos_rel = (const float*)d_in[1];
  const float* h0   = (const float*)d_in[2];
  const float* c0   = (const float*)d_in[3];
  const float* W_se = (const float*)d_in[5];
  const float* b_se = (const float*)d_in[6];
  const float* W_ih = (const float*)d_in[7];
  const float* b_ih = (const float*)d_in[8];
  const float* W_hh = (const float*)d_in[9];
  const float* b_hh = (const float*)d_in[10];
  const float* W_hp = (const float*)d_in[11];
  const float* b_hp = (const float*)d_in[12];
  const float* W_pse = (const float*)d_in[13];
  const float* b_pse = (const float*)d_in[14];
  const float* W_p1 = (const float*)d_in[15];
  const float* b_p1 = (const float*)d_in[16];
  const float* W_p2 = (const float*)d_in[17];
  const float* b_p2 = (const float*)d_in[18];
  const float* W_m1 = (const float*)d_in[19];
  const float* b_m1 = (const float*)d_in[20];
  const float* W_m2 = (const float*)d_in[21];
  const float* b_m2 = (const float*)d_in[22];

  float* ws = (float*)d_ws;
  float* hacc[2]  = { ws,           ws + 98304 };
  float* ccar[2]  = { ws + 196608,  ws + 294912 };
  float* din[2]   = { ws + 393216,  ws + 442368 };
  float* lposb[2] = { ws + 491520,  ws + 493056 };
  float* hn   = ws + 494592;
  float* Hp1  = ws + 592896;
  float* ph   = ws + 986112;
  float* Wc   = ws + 1772544;
  float* bc   = ws + 1773568;
  unsigned short* W2T = (unsigned short*)(ws + 1774080);  // 1024x512 bf16
  unsigned short* W1T = (unsigned short*)(ws + 2036224);  // 1024x1152 bf16
  unsigned short* WmT = (unsigned short*)(ws + 2626048);  // 128x1024 bf16

  float* pred = (float*)d_out;

  init_kernel<<<128, 256, 0, stream>>>(last_pos, last_pos_rel, c0,
                                       W_se, b_se, W_pse, b_pse, W_p1, b_p1,
                                       W_p2, W_m1, W_m2,
                                       ccar[0], din[0], lposb[0],
                                       Wc, bc, W2T, W1T, WmT);

  for (int t = 0; t < TSTEPS; ++t) {
    int a = t & 1, b = (t + 1) & 1;
    step_a<<<NB / AR, 256, 0, stream>>>(
        t == 0 ? h0 : hacc[a], ccar[a], din[a], lposb[a],
        W_ih, b_ih, W_hh, b_hh, W_hp, b_hp, W_se, b_se, W_p1, bc, b_m2,
        hn, ccar[b], din[b], lposb[b], Hp1, pred + t * NB * 2,
        hacc[b], t == 0 ? 0 : 1);
    pool_mfma<<<NS * 24, 256, 0, stream>>>(lposb[b], Hp1, Wc, W2T, b_p2, ph);
    mlp1_fused<<<192, 256, 0, stream>>>(hn, ph, W1T, b_m1, WmT, hacc[b]);
  }

  final_h<<<384, 256, 0, stream>>>(hacc[0], (float*)d_out + TSTEPS * NB * 2);
}

// Round 7
// 1362.389 us; speedup vs baseline: 1.3854x; 1.0776x over previous
//
#include <hip/hip_runtime.h>
#include <math.h>

// Problem constants (uniform scenes per reference)
#define NB 768      // batch = S*P
#define NS 32       // scenes
#define NP 24       // peds/scene
#define ED 64       // embedding dim E
#define HD 128      // hidden H
#define G4 512      // 4*H
#define BNKD 1024   // bottleneck
#define KM1 1152    // H + BNK
#define TSTEPS 12
#define AR 4        // rows per step_a block
#define BPITCH 516  // LDS row pitch in shorts (1032B = 258 words == 2 mod 32)

typedef __bf16 bf16x8 __attribute__((ext_vector_type(8)));
typedef float f32x4 __attribute__((ext_vector_type(4)));
typedef unsigned short u16x8 __attribute__((ext_vector_type(8)));

__device__ __forceinline__ unsigned short f2bf(float f) {
  unsigned u = __float_as_uint(f);
  u = (u + 0x7FFFu + ((u >> 16) & 1u)) >> 16;   // RNE
  return (unsigned short)u;
}
__device__ __forceinline__ unsigned pack2bf(float a, float b) {
  return (unsigned)f2bf(a) | ((unsigned)f2bf(b) << 16);
}
__device__ __forceinline__ float bf2f(unsigned short h) {
  return __uint_as_float(((unsigned)h) << 16);
}

// ---------------------------------------------------------------------------
// init: carries, dec_in0, folded pool-L1 weights (Wc = W_pse@W_p1[:64], bc),
// bf16-transposed W2T[n][k]=W_p2[k][n], W1T[n][k]=W_m1[k][n], WmT[n][k]=W_m2[k][n]
// ---------------------------------------------------------------------------
__global__ void init_kernel(const float* __restrict__ last_pos,
                            const float* __restrict__ last_pos_rel,
                            const float* __restrict__ c0,
                            const float* __restrict__ W_se,
                            const float* __restrict__ b_se,
                            const float* __restrict__ W_pse,
                            const float* __restrict__ b_pse,
                            const float* __restrict__ W_p1,
                            const float* __restrict__ b_p1,
                            const float* __restrict__ W_p2,
                            const float* __restrict__ W_m1,
                            const float* __restrict__ W_m2,
                            float* __restrict__ ccar,
                            float* __restrict__ din, float* __restrict__ lpos,
                            float* __restrict__ Wc, float* __restrict__ bc,
                            unsigned short* __restrict__ W2T,
                            unsigned short* __restrict__ W1T,
                            unsigned short* __restrict__ WmT) {
  int stride = gridDim.x * blockDim.x;
  int idx0 = blockIdx.x * blockDim.x + threadIdx.x;
  for (int i = idx0; i < NB * HD; i += stride) ccar[i] = c0[i];
  for (int i = idx0; i < NB * 2; i += stride) lpos[i] = last_pos[i];
  for (int i = idx0; i < NB * ED; i += stride) {
    int r = i >> 6, e = i & 63;
    din[i] = b_se[e] + last_pos_rel[2 * r] * W_se[e]
                     + last_pos_rel[2 * r + 1] * W_se[ED + e];
  }
  for (int n = idx0; n < G4; n += stride) {
    float w0 = 0.f, w1 = 0.f, bb = b_p1[n];
    for (int e = 0; e < ED; ++e) {
      float wp = W_p1[e * G4 + n];
      w0 += W_pse[e] * wp;
      w1 += W_pse[ED + e] * wp;
      bb += b_pse[e] * wp;
    }
    Wc[n] = w0; Wc[G4 + n] = w1; bc[n] = bb;
  }
  // W2T: 1024 n x 512 k bf16
  for (int idx = idx0; idx < 1024 * 64; idx += stride) {
    int n = idx & 1023, k0 = (idx >> 10) << 3;
    unsigned pk0 = pack2bf(W_p2[(k0 + 0) * BNKD + n], W_p2[(k0 + 1) * BNKD + n]);
    unsigned pk1 = pack2bf(W_p2[(k0 + 2) * BNKD + n], W_p2[(k0 + 3) * BNKD + n]);
    unsigned pk2 = pack2bf(W_p2[(k0 + 4) * BNKD + n], W_p2[(k0 + 5) * BNKD + n]);
    unsigned pk3 = pack2bf(W_p2[(k0 + 6) * BNKD + n], W_p2[(k0 + 7) * BNKD + n]);
    *(uint4*)&W2T[n * G4 + k0] = make_uint4(pk0, pk1, pk2, pk3);
  }
  // W1T: 1024 n x 1152 k bf16
  for (int idx = idx0; idx < 1024 * 144; idx += stride) {
    int n = idx & 1023, k0 = (idx >> 10) << 3;
    unsigned pk0 = pack2bf(W_m1[(k0 + 0) * BNKD + n], W_m1[(k0 + 1) * BNKD + n]);
    unsigned pk1 = pack2bf(W_m1[(k0 + 2) * BNKD + n], W_m1[(k0 + 3) * BNKD + n]);
    unsigned pk2 = pack2bf(W_m1[(k0 + 4) * BNKD + n], W_m1[(k0 + 5) * BNKD + n]);
    unsigned pk3 = pack2bf(W_m1[(k0 + 6) * BNKD + n], W_m1[(k0 + 7) * BNKD + n]);
    *(uint4*)&W1T[n * KM1 + k0] = make_uint4(pk0, pk1, pk2, pk3);
  }
  // WmT: 128 n x 1024 k bf16   (W_m2 is [1024][128])
  for (int idx = idx0; idx < 128 * 128; idx += stride) {
    int n = idx & 127, k0 = (idx >> 7) << 3;
    unsigned pk0 = pack2bf(W_m2[(k0 + 0) * HD + n], W_m2[(k0 + 1) * HD + n]);
    unsigned pk1 = pack2bf(W_m2[(k0 + 2) * HD + n], W_m2[(k0 + 3) * HD + n]);
    unsigned pk2 = pack2bf(W_m2[(k0 + 4) * HD + n], W_m2[(k0 + 5) * HD + n]);
    unsigned pk3 = pack2bf(W_m2[(k0 + 6) * HD + n], W_m2[(k0 + 7) * HD + n]);
    *(uint4*)&WmT[n * BNKD + k0] = make_uint4(pk0, pk1, pk2, pk3);
  }
}

// ---------------------------------------------------------------------------
// step A: LSTM cell (h read = relu(hacc_prev) unless first step) + rel/curr pos
// + dec_in_next + Hp1 = h_new @ W_p1[64:] + bc + hacc_next init = b_m2.
// 4 rows/block, grid 192.
// ---------------------------------------------------------------------------
__global__ __launch_bounds__(256) void step_a(
    const float* __restrict__ hprev, const float* __restrict__ cprev,
    const float* __restrict__ din, const float* __restrict__ lpos_in,
    const float* __restrict__ W_ih, const float* __restrict__ b_ih,
    const float* __restrict__ W_hh, const float* __restrict__ b_hh,
    const float* __restrict__ W_hp, const float* __restrict__ b_hp,
    const float* __restrict__ W_se, const float* __restrict__ b_se,
    const float* __restrict__ W_p1, const float* __restrict__ bc,
    const float* __restrict__ b_m2,
    float* __restrict__ hn, float* __restrict__ cnext,
    float* __restrict__ dnext, float* __restrict__ lpos_out,
    float* __restrict__ Hp1, float* __restrict__ pred_out,
    float* __restrict__ hacc_next, int relu_in) {
  __shared__ float x[AR][192];   // [din(64) | h(128)]
  __shared__ float gg[AR][G4];
  __shared__ float hl[AR][HD];
  __shared__ float rp[AR][2];
  int t = threadIdx.x;
  int r0 = blockIdx.x * AR;

  for (int i = t; i < AR * ED; i += 256) { int r = i >> 6, k = i & 63; x[r][k] = din[(r0 + r) * ED + k]; }
  for (int i = t; i < AR * HD; i += 256) {
    int r = i >> 7, k = i & 127;
    float v = hprev[(r0 + r) * HD + k];
    if (relu_in) v = fmaxf(v, 0.f);
    x[r][ED + k] = v;
    hacc_next[(r0 + r) * HD + k] = b_m2[k];   // bias-init mlp2 accumulator
  }
  __syncthreads();

  float acc[AR][2];
#pragma unroll
  for (int r = 0; r < AR; ++r) { acc[r][0] = b_ih[t] + b_hh[t]; acc[r][1] = b_ih[t + 256] + b_hh[t + 256]; }
  for (int k = 0; k < ED; ++k) {
    float w0 = W_ih[k * G4 + t], w1 = W_ih[k * G4 + t + 256];
#pragma unroll
    for (int r = 0; r < AR; ++r) { float a = x[r][k]; acc[r][0] += a * w0; acc[r][1] += a * w1; }
  }
  for (int k = 0; k < HD; ++k) {
    float w0 = W_hh[k * G4 + t], w1 = W_hh[k * G4 + t + 256];
#pragma unroll
    for (int r = 0; r < AR; ++r) { float a = x[r][ED + k]; acc[r][0] += a * w0; acc[r][1] += a * w1; }
  }
#pragma unroll
  for (int r = 0; r < AR; ++r) { gg[r][t] = acc[r][0]; gg[r][t + 256] = acc[r][1]; }
  __syncthreads();

  for (int i = t; i < AR * HD; i += 256) {
    int r = i >> 7, k = i & 127;
    float ig = gg[r][k], fg = gg[r][HD + k], gz = gg[r][2 * HD + k], og = gg[r][3 * HD + k];
    float si = 1.f / (1.f + expf(-ig));
    float sf = 1.f / (1.f + expf(-fg));
    float so = 1.f / (1.f + expf(-og));
    float gt = tanhf(gz);
    float c = sf * cprev[(r0 + r) * HD + k] + si * gt;
    float h = so * tanhf(c);
    cnext[(r0 + r) * HD + k] = c;
    hn[(r0 + r) * HD + k] = h;
    hl[r][k] = h;
  }
  __syncthreads();

  if (t < AR * 2) {
    int r = t >> 1, d = t & 1;
    float s = b_hp[d];
    for (int k = 0; k < HD; ++k) s += hl[r][k] * W_hp[k * 2 + d];
    rp[r][d] = s;
    pred_out[(r0 + r) * 2 + d] = s;
    lpos_out[(r0 + r) * 2 + d] = s + lpos_in[(r0 + r) * 2 + d];
  }
  __syncthreads();

  for (int i = t; i < AR * ED; i += 256) {
    int r = i >> 6, e = i & 63;
    dnext[(r0 + r) * ED + e] = b_se[e] + rp[r][0] * W_se[e] + rp[r][1] * W_se[ED + e];
  }

  // Hp1 = h_new @ W_p1[64:192] + bc   (bc folded here)
  float bc0 = bc[t], bc1 = bc[t + 256];
  float acc2[AR][2];
#pragma unroll
  for (int r = 0; r < AR; ++r) { acc2[r][0] = bc0; acc2[r][1] = bc1; }
  for (int k = 0; k < HD; ++k) {
    float w0 = W_p1[(ED + k) * G4 + t], w1 = W_p1[(ED + k) * G4 + t + 256];
#pragma unroll
    for (int r = 0; r < AR; ++r) { float a = hl[r][k]; acc2[r][0] += a * w0; acc2[r][1] += a * w1; }
  }
#pragma unroll
  for (int r = 0; r < AR; ++r) {
    Hp1[(r0 + r) * G4 + t] = acc2[r][0];
    Hp1[(r0 + r) * G4 + t + 256] = acc2[r][1];
  }
}

// ---------------------------------------------------------------------------
// pool_mfma v5: block = (scene, 128-col n-tile); grid 256 = 1 block/CU.
// Stage ONCE into LDS: B tile (128x512 bf16), scene Hp1 (24x512 bf16), Wc.
// Then zero-barrier main loop: 4 waves x 3 i-pairs; A-frags generated
// in-register from LDS Hp1/Wc; B-frags via conflict-free ds_read_b128.
// Per-CU global traffic ~160KB (was 1.5MB) -> beats the 10 B/cyc/CU wall.
// ---------------------------------------------------------------------------
__global__ __launch_bounds__(256, 1) void pool_mfma(
    const float* __restrict__ curr_pos, const float* __restrict__ Hp1,
    const float* __restrict__ Wc,
    const unsigned short* __restrict__ W2T, const float* __restrict__ b_p2,
    float* __restrict__ pool_h) {
  __shared__ __align__(16) unsigned short Bl[128 * BPITCH];   // 132096 B
  __shared__ __align__(16) unsigned short Hps[24 * BPITCH];   // 24768 B
  __shared__ __align__(16) float wc0s[G4], wc1s[G4];          // 4096 B
  __shared__ float psx[NP], psy[NP];
  int t = threadIdx.x;
  int b = blockIdx.x;              // 256 = 32 scenes * 8 ntiles
  int s = b >> 3, nt = b & 7;
  int n0 = nt * 128;

  // stage B: 128 rows x 512 k (coalesced 16B)
  for (int idx = t; idx < 128 * 64; idx += 256) {
    int row = idx >> 6, ch = (idx & 63) << 3;
    *(uint4*)&Bl[row * BPITCH + ch] = *(const uint4*)&W2T[(size_t)(n0 + row) * G4 + ch];
  }
  // stage Hp1 (fp32 -> bf16)
  for (int idx = t; idx < 24 * 64; idx += 256) {
    int row = idx >> 6, ch = (idx & 63) << 3;
    const float* src = &Hp1[(size_t)(s * NP + row) * G4 + ch];
    float4 v0 = *(const float4*)src;
    float4 v1 = *(const float4*)(src + 4);
    uint4 pk;
    pk.x = pack2bf(v0.x, v0.y); pk.y = pack2bf(v0.z, v0.w);
    pk.z = pack2bf(v1.x, v1.y); pk.w = pack2bf(v1.z, v1.w);
    *(uint4*)&Hps[row * BPITCH + ch] = pk;
  }
  if (t < 128) {
    *(float4*)&wc0s[t * 4] = *(const float4*)&Wc[t * 4];
    *(float4*)&wc1s[t * 4] = *(const float4*)&Wc[G4 + t * 4];
  }
  if (t < NP) {
    psx[t] = curr_pos[(s * NP + t) * 2];
    psy[t] = curr_pos[(s * NP + t) * 2 + 1];
  }
  __syncthreads();

  int lane = t & 63, wv = t >> 6;
  int arow = lane & 15, ak = (lane >> 4) * 8;
  int h = lane >> 4;

  int boff[8];
#pragma unroll
  for (int nf = 0; nf < 8; ++nf) boff[nf] = (nf * 16 + arow) * BPITCH + ak;

  for (int c = 0; c < 3; ++c) {
    int ip = wv * 3 + c;               // i-pair 0..11
    float rx[3], ry[3];
    int hoff[3];
#pragma unroll
    for (int f = 0; f < 3; ++f) {
      int m = f * 16 + arow;
      int j = m % 24, g = m / 24;
      rx[f] = psx[j] - psx[ip * 2 + g];
      ry[f] = psy[j] - psy[ip * 2 + g];
      hoff[f] = j * BPITCH + ak;
    }
    f32x4 acc[3][8];
#pragma unroll
    for (int f = 0; f < 3; ++f)
#pragma unroll
      for (int nf = 0; nf < 8; ++nf) acc[f][nf] = (f32x4){0.f, 0.f, 0.f, 0.f};

#pragma unroll 2
    for (int kt = 0; kt < 16; ++kt) {
      int k0 = kt * 32;
      float4 wa = *(const float4*)&wc0s[k0 + ak];
      float4 wb = *(const float4*)&wc0s[k0 + ak + 4];
      float4 va = *(const float4*)&wc1s[k0 + ak];
      float4 vb = *(const float4*)&wc1s[k0 + ak + 4];
      bf16x8 af[3];
#pragma unroll
      for (int f = 0; f < 3; ++f) {
        u16x8 hp = *(const u16x8*)&Hps[hoff[f] + k0];
        float rxf = rx[f], ryf = ry[f];
        af[f][0] = (__bf16)fmaxf(bf2f(hp[0]) + rxf * wa.x + ryf * va.x, 0.f);
        af[f][1] = (__bf16)fmaxf(bf2f(hp[1]) + rxf * wa.y + ryf * va.y, 0.f);
        af[f][2] = (__bf16)fmaxf(bf2f(hp[2]) + rxf * wa.z + ryf * va.z, 0.f);
        af[f][3] = (__bf16)fmaxf(bf2f(hp[3]) + rxf * wa.w + ryf * va.w, 0.f);
        af[f][4] = (__bf16)fmaxf(bf2f(hp[4]) + rxf * wb.x + ryf * vb.x, 0.f);
        af[f][5] = (__bf16)fmaxf(bf2f(hp[5]) + rxf * wb.y + ryf * vb.y, 0.f);
        af[f][6] = (__bf16)fmaxf(bf2f(hp[6]) + rxf * wb.z + ryf * vb.z, 0.f);
        af[f][7] = (__bf16)fmaxf(bf2f(hp[7]) + rxf * wb.w + ryf * vb.w, 0.f);
      }
      bf16x8 bfr[8];
#pragma unroll
      for (int nf = 0; nf < 8; ++nf) bfr[nf] = *(const bf16x8*)&Bl[boff[nf] + k0];
#pragma unroll
      for (int nf = 0; nf < 8; ++nf)
#pragma unroll
        for (int f = 0; f < 3; ++f)
          acc[f][nf] = __builtin_amdgcn_mfma_f32_16x16x32_bf16(af[f], bfr[nf], acc[f][nf], 0, 0, 0);
    }

    // epilogue: max over j per ped group. frag rows: f0=g0 j0-15,
    // f1 lo=g0 j16-23 / hi=g1 j0-7, f2=g1 j8-23. C: row=(lane>>4)*4+reg.
    int iA = s * NP + ip * 2;
#pragma unroll
    for (int nf = 0; nf < 8; ++nf) {
      f32x4 a0 = acc[0][nf], a1 = acc[1][nf], a2 = acc[2][nf];
      float v0 = fmaxf(fmaxf(a0[0], a0[1]), fmaxf(a0[2], a0[3]));
      float v1 = fmaxf(fmaxf(a1[0], a1[1]), fmaxf(a1[2], a1[3]));
      float v2 = fmaxf(fmaxf(a2[0], a2[1]), fmaxf(a2[2], a2[3]));
      v0 = fmaxf(v0, __shfl_xor(v0, 16));
      v1 = fmaxf(v1, __shfl_xor(v1, 16));
      v2 = fmaxf(v2, __shfl_xor(v2, 16));
      float xx = (h < 2) ? fmaxf(v0, v1) : v0;    // g0 = f0 all + f1 lo
      xx = fmaxf(xx, __shfl_xor(xx, 32));
      float yy = (h >= 2) ? fmaxf(v2, v1) : v2;   // g1 = f1 hi + f2 all
      yy = fmaxf(yy, __shfl_xor(yy, 32));
      int col = n0 + nf * 16 + (lane & 15);
      float bb = b_p2[col];
      xx = fmaxf(xx + bb, 0.f);
      yy = fmaxf(yy + bb, 0.f);
      if (h == 0) pool_h[(size_t)iA * BNKD + col] = xx;
      if (h == 1) pool_h[((size_t)iA + 1) * BNKD + col] = yy;
    }
  }
}

// ---------------------------------------------------------------------------
// mlp1_fused: stage1 mh_tile = relu([hn|ph] @ W_m1 + b_m1) (32x128, regs),
// stage2 hacc += mh_tile @ W_m2[n0:n0+128, :] via bf16 hi+lo MFMA + atomicAdd.
// ---------------------------------------------------------------------------
__global__ __launch_bounds__(256) void mlp1_fused(
    const float* __restrict__ hn, const float* __restrict__ ph,
    const unsigned short* __restrict__ W1T, const float* __restrict__ b_m1,
    const unsigned short* __restrict__ WmT, float* __restrict__ hacc) {
  __shared__ __align__(16) float Pl[32][132];
  int t = threadIdx.x, b = blockIdx.x;   // 192 = 24 mt * 8 nt
  int mt = b >> 3, nt = b & 7;
  int r0 = mt * 32, n0 = nt * 128;
  int lane = t & 63, wid = t >> 6, wm = wid >> 1, wn = wid & 1;
  int arow = lane & 15, ak = (lane >> 4) * 8;
  int h = lane >> 4;

  f32x4 acc0[4];
#pragma unroll
  for (int nf = 0; nf < 4; ++nf) acc0[nf] = (f32x4){0.f, 0.f, 0.f, 0.f};
  int mrow = r0 + wm * 16 + arow;
  const unsigned short* bp[4];
#pragma unroll
  for (int nf = 0; nf < 4; ++nf)
    bp[nf] = W1T + (size_t)(n0 + wn * 64 + nf * 16 + arow) * KM1 + ak;
  const float* arow_h = hn + (size_t)mrow * HD;
  const float* arow_p = ph + (size_t)mrow * BNKD - HD;  // biased so [kg] works

  for (int kt = 0; kt < 36; ++kt) {
    int kg = kt * 32 + ak;
    const float* src = (kg < HD) ? arow_h : arow_p;
    float4 v0 = *(const float4*)&src[kg];
    float4 v1 = *(const float4*)&src[kg + 4];
    u16x8 ua;
    ua[0] = f2bf(v0.x); ua[1] = f2bf(v0.y); ua[2] = f2bf(v0.z); ua[3] = f2bf(v0.w);
    ua[4] = f2bf(v1.x); ua[5] = f2bf(v1.y); ua[6] = f2bf(v1.z); ua[7] = f2bf(v1.w);
    bf16x8 a = __builtin_bit_cast(bf16x8, ua);
#pragma unroll
    for (int nf = 0; nf < 4; ++nf) {
      bf16x8 bb = *(const bf16x8*)(bp[nf] + kt * 32);
      acc0[nf] = __builtin_amdgcn_mfma_f32_16x16x32_bf16(a, bb, acc0[nf], 0, 0, 0);
    }
  }

  // P = relu(acc0 + b_m1) -> LDS (fp32)
#pragma unroll
  for (int nf = 0; nf < 4; ++nf) {
    int colp = wn * 64 + nf * 16 + arow;
    float bb = b_m1[n0 + colp];
#pragma unroll
    for (int rr = 0; rr < 4; ++rr)
      Pl[wm * 16 + h * 4 + rr][colp] = fmaxf(acc0[nf][rr] + bb, 0.f);
  }
  __syncthreads();

  // stage 2: (32x128 P-tile) @ WmT[:, n0:n0+128]^T -> 32x128 partial of h
  f32x4 acc2[4];
#pragma unroll
  for (int nf = 0; nf < 4; ++nf) acc2[nf] = (f32x4){0.f, 0.f, 0.f, 0.f};
  const unsigned short* b2p[4];
#pragma unroll
  for (int nf = 0; nf < 4; ++nf)
    b2p[nf] = WmT + (size_t)(wn * 64 + nf * 16 + arow) * BNKD + n0 + ak;
  const float* prow = &Pl[wm * 16 + arow][0];

#pragma unroll
  for (int k2 = 0; k2 < 4; ++k2) {
    u16x8 uh, ul;
#pragma unroll
    for (int q = 0; q < 8; ++q) {
      float vv = prow[k2 * 32 + ak + q];
      unsigned short hh = f2bf(vv);
      uh[q] = hh;
      ul[q] = f2bf(vv - bf2f(hh));
    }
    bf16x8 ahi = __builtin_bit_cast(bf16x8, uh);
    bf16x8 alo = __builtin_bit_cast(bf16x8, ul);
#pragma unroll
    for (int nf = 0; nf < 4; ++nf) {
      bf16x8 bb = *(const bf16x8*)(b2p[nf] + k2 * 32);
      acc2[nf] = __builtin_amdgcn_mfma_f32_16x16x32_bf16(ahi, bb, acc2[nf], 0, 0, 0);
      acc2[nf] = __builtin_amdgcn_mfma_f32_16x16x32_bf16(alo, bb, acc2[nf], 0, 0, 0);
    }
  }
#pragma unroll
  for (int nf = 0; nf < 4; ++nf)
#pragma unroll
    for (int rr = 0; rr < 4; ++rr)
      atomicAdd(&hacc[(size_t)(r0 + wm * 16 + h * 4 + rr) * HD + wn * 64 + nf * 16 + arow],
                acc2[nf][rr]);
}

// ---------------------------------------------------------------------------
// final: h_fin = relu(hacc)
// ---------------------------------------------------------------------------
__global__ void final_h(const float* __restrict__ hacc, float* __restrict__ out) {
  int i = blockIdx.x * 256 + threadIdx.x;
  if (i < NB * HD) out[i] = fmaxf(hacc[i], 0.f);
}

// ---------------------------------------------------------------------------
extern "C" void kernel_launch(void* const* d_in, const int* in_sizes, int n_in,
                              void* d_out, int out_size, void* d_ws, size_t ws_size,
                              hipStream_t stream) {
  const float* last_pos     = (const float*)d_in[0];
  const float* last_pos_rel = (const float*)d_in[1];
  const float* h0   = (const float*)d_in[2];
  const float* c0   = (const float*)d_in[3];
  const float* W_se = (const float*)d_in[5];
  const float* b_se = (const float*)d_in[6];
  const float* W_ih = (const float*)d_in[7];
  const float* b_ih = (const float*)d_in[8];
  const float* W_hh = (const float*)d_in[9];
  const float* b_hh = (const float*)d_in[10];
  const float* W_hp = (const float*)d_in[11];
  const float* b_hp = (const float*)d_in[12];
  const float* W_pse = (const float*)d_in[13];
  const float* b_pse = (const float*)d_in[14];
  const float* W_p1 = (const float*)d_in[15];
  const float* b_p1 = (const float*)d_in[16];
  const float* W_p2 = (const float*)d_in[17];
  const float* b_p2 = (const float*)d_in[18];
  const float* W_m1 = (const float*)d_in[19];
  const float* b_m1 = (const float*)d_in[20];
  const float* W_m2 = (const float*)d_in[21];
  const float* b_m2 = (const float*)d_in[22];

  float* ws = (float*)d_ws;
  float* hacc[2]  = { ws,           ws + 98304 };
  float* ccar[2]  = { ws + 196608,  ws + 294912 };
  float* din[2]   = { ws + 393216,  ws + 442368 };
  float* lposb[2] = { ws + 491520,  ws + 493056 };
  float* hn   = ws + 494592;
  float* Hp1  = ws + 592896;
  float* ph   = ws + 986112;
  float* Wc   = ws + 1772544;
  float* bc   = ws + 1773568;
  unsigned short* W2T = (unsigned short*)(ws + 1774080);  // 1024x512 bf16
  unsigned short* W1T = (unsigned short*)(ws + 2036224);  // 1024x1152 bf16
  unsigned short* WmT = (unsigned short*)(ws + 2626048);  // 128x1024 bf16

  float* pred = (float*)d_out;

  init_kernel<<<128, 256, 0, stream>>>(last_pos, last_pos_rel, c0,
                                       W_se, b_se, W_pse, b_pse, W_p1, b_p1,
                                       W_p2, W_m1, W_m2,
                                       ccar[0], din[0], lposb[0],
                                       Wc, bc, W2T, W1T, WmT);

  for (int t = 0; t < TSTEPS; ++t) {
    int a = t & 1, b = (t + 1) & 1;
    step_a<<<NB / AR, 256, 0, stream>>>(
        t == 0 ? h0 : hacc[a], ccar[a], din[a], lposb[a],
        W_ih, b_ih, W_hh, b_hh, W_hp, b_hp, W_se, b_se, W_p1, bc, b_m2,
        hn, ccar[b], din[b], lposb[b], Hp1, pred + t * NB * 2,
        hacc[b], t == 0 ? 0 : 1);
    pool_mfma<<<NS * 8, 256, 0, stream>>>(lposb[b], Hp1, Wc, W2T, b_p2, ph);
    mlp1_fused<<<192, 256, 0, stream>>>(hn, ph, W1T, b_m1, WmT, hacc[b]);
  }

  final_h<<<384, 256, 0, stream>>>(hacc[0], (float*)d_out + TSTEPS * NB * 2);
}